// Round 1
// baseline (12805.273 us; speedup 1.0000x reference)
//
#include <hip/hip_runtime.h>
#include <hip/hip_bf16.h>

// ContTimeLSTM: L=512, B=32, DIN=512, H=1024.
// Persistent kernel: 128 WGs x 512 threads; WG g owns h-columns [8g, 8g+8)
// => 48 weight rows (6 gates x 8 cols) resident in LDS as swizzled bf16.
// One device-wide spin barrier per timestep.

#define L_STEPS 512
#define BATCH   32
#define DIN     512
#define HDIM    1024
#define KDIM    1536     // DIN + HDIM
#define NWG     128
#define CPW     8        // h-cols per WG
#define NLOC    48       // 6*CPW weight rows per WG
#define NTHREADS 512     // 8 waves: 6 gate-tile waves + 2 d-waves
#define WROW_BYTES 3072  // KDIM * 2B

// LDS layout (bytes)
#define LDS_DW   147456                  // after W (48*3072)
#define LDS_PROJ 150528                  // after dw (1536*2)
#define LDS_D    156864                  // after proj (48*33*4)
#define LDS_BYTES 157056

typedef __attribute__((ext_vector_type(8))) __bf16 bf16x8;
typedef __attribute__((ext_vector_type(4))) float  f32x4;

__device__ __forceinline__ float fsigmoid(float u) { return 1.0f / (1.0f + __expf(-u)); }

extern "C" __global__ void __launch_bounds__(NTHREADS, 1)
ctlstm_kernel(const float* __restrict__ x,
              const float* __restrict__ tdel,
              const float* __restrict__ o_state,
              const float* __restrict__ cs_state,
              const float* __restrict__ ce_state,
              const float* __restrict__ d_state,
              const float* __restrict__ weight,
              const float* __restrict__ bias,
              const float* __restrict__ d_weight,
              const float* __restrict__ d_bias,
              const float* __restrict__ d_beta_p,
              float* __restrict__ out0,
              float* __restrict__ out1,
              unsigned int* __restrict__ cnt,
              __bf16* __restrict__ h0,
              __bf16* __restrict__ h1)
{
    extern __shared__ char smem[];
    char*   Wsm  = smem;
    __bf16* dwsm = (__bf16*)(smem + LDS_DW);
    float*  proj = (float*)(smem + LDS_PROJ);
    float*  dls  = (float*)(smem + LDS_D);

    const int tid = threadIdx.x;
    const int wg  = blockIdx.x;
    const int c0  = wg * CPW;

    // ---- startup: stage this WG's 48 weight rows into LDS (bf16, XOR-swizzled) ----
    for (int u = tid; u < NLOC * (KDIM / 4); u += NTHREADS) {
        int rrow = u / (KDIM / 4);
        int k4   = u - rrow * (KDIM / 4);
        int g = rrow >> 3, jj = rrow & 7;
        const float4 f = *(const float4*)(weight + (size_t)(g * HDIM + c0 + jj) * KDIM + k4 * 4);
        __bf16 b0 = (__bf16)f.x, b1 = (__bf16)f.y, b2 = (__bf16)f.z, b3 = (__bf16)f.w;
        unsigned short u0 = __builtin_bit_cast(unsigned short, b0);
        unsigned short u1 = __builtin_bit_cast(unsigned short, b1);
        unsigned short u2 = __builtin_bit_cast(unsigned short, b2);
        unsigned short u3 = __builtin_bit_cast(unsigned short, b3);
        uint2 v;
        v.x = (unsigned)u0 | ((unsigned)u1 << 16);
        v.y = (unsigned)u2 | ((unsigned)u3 << 16);
        unsigned boff = (unsigned)rrow * WROW_BYTES +
                        (((unsigned)(k4 * 8)) ^ (((unsigned)(rrow & 15)) << 4));
        *(uint2*)(Wsm + boff) = v;
    }
    for (int u = tid; u < KDIM; u += NTHREADS) dwsm[u] = (__bf16)d_weight[u];
    if (tid < BATCH) dls[tid] = d_state[tid];

    // ---- per-thread persistent state (threads 0..255 own (b, j)) ----
    float s_o = 0.f, s_cs = 0.f, s_ce = 0.f;
    const int b = tid >> 3, j = tid & 7;
    if (tid < 256) {
        int gi = b * HDIM + c0 + j;
        s_o = o_state[gi]; s_cs = cs_state[gi]; s_ce = ce_state[gi];
    }

    // ---- wave identities ----
    const int wv  = tid >> 6;        // 0..7
    const int l   = tid & 63;
    const int mT  = wv & 1;          // batch-tile
    const int nT  = wv >> 1;         // 0..2 gate tiles; 3 => d-waves
    const int row = mT * 16 + (l & 15);
    const int kg  = l >> 4;
    const int nl  = nT * 16 + (l & 15);   // n-local 0..47 (gate waves)
    float bias_r = 0.f;
    if (wv < 6) bias_r = bias[(nl >> 3) * HDIM + c0 + (nl & 7)];
    const float dbias_s = d_bias[0];
    const float beta    = d_beta_p[0];
    const unsigned xorv  = ((unsigned)(nl & 15)) << 4;
    const unsigned wbase = (unsigned)nl * WROW_BYTES;

    __syncthreads();

    float c_reg = 0.f;
    for (int t = 0; t < L_STEPS; ++t) {
        __bf16* hcur = (t & 1) ? h1 : h0;

        // ---- phase 1: c, h from previous state; publish h slice ----
        if (tid < 256) {
            float dt = tdel[t * BATCH + b];
            float dv = dls[b];
            float c  = s_cs + (s_ce - s_cs) * __expf(-dv * dt);
            float h  = s_o * (1.f - 2.f / (__expf(2.f * c) + 1.f));  // o * tanh(c)
            c_reg = c;
            hcur[b * HDIM + c0 + j] = (__bf16)h;
            __builtin_nontemporal_store(h, out0 + ((size_t)b * L_STEPS + t) * HDIM + c0 + j);
        }
        __syncthreads();

        // ---- device-wide barrier (one per step) ----
        if (tid == 0) {
            __hip_atomic_fetch_add(cnt, 1u, __ATOMIC_RELEASE, __HIP_MEMORY_SCOPE_AGENT);
            const unsigned tgt = (unsigned)NWG * (unsigned)(t + 1);
            while (__hip_atomic_load(cnt, __ATOMIC_RELAXED, __HIP_MEMORY_SCOPE_AGENT) < tgt)
                __builtin_amdgcn_s_sleep(1);
            __builtin_amdgcn_fence(__ATOMIC_ACQUIRE, "agent");
        }
        __syncthreads();

        // ---- phase 3: MFMA over K = [x (512) | h (1024)] ----
        const float*  xrow = x + ((size_t)t * BATCH + row) * DIN;
        const __bf16* hrow = hcur + row * HDIM;
        f32x4 acc  = {0.f, 0.f, 0.f, 0.f};

        if (wv < 6) {
            #pragma unroll
            for (int kc = 0; kc < 16; ++kc) {            // x part (fp32 -> bf16)
                const int k = kc * 32 + kg * 8;
                float4 fa = *(const float4*)(xrow + k);
                float4 fb = *(const float4*)(xrow + k + 4);
                bf16x8 af;
                af[0] = (__bf16)fa.x; af[1] = (__bf16)fa.y; af[2] = (__bf16)fa.z; af[3] = (__bf16)fa.w;
                af[4] = (__bf16)fb.x; af[5] = (__bf16)fb.y; af[6] = (__bf16)fb.z; af[7] = (__bf16)fb.w;
                const unsigned koff = (unsigned)(kc * 64 + kg * 16);
                bf16x8 bf = *(const bf16x8*)(Wsm + (wbase + (koff ^ xorv)));
                acc = __builtin_amdgcn_mfma_f32_16x16x32_bf16(af, bf, acc, 0, 0, 0);
            }
            #pragma unroll 8
            for (int kc = 16; kc < 48; ++kc) {           // h part (bf16 direct)
                const int k = kc * 32 + kg * 8;
                bf16x8 af = *(const bf16x8*)(hrow + (k - DIN));
                const unsigned koff = (unsigned)(kc * 64 + kg * 16);
                bf16x8 bf = *(const bf16x8*)(Wsm + (wbase + (koff ^ xorv)));
                acc = __builtin_amdgcn_mfma_f32_16x16x32_bf16(af, bf, acc, 0, 0, 0);
            }
            #pragma unroll
            for (int r = 0; r < 4; ++r) {
                float p = fsigmoid(acc[r] + bias_r);
                proj[nl * 33 + mT * 16 + kg * 4 + r] = p;
            }
        } else {
            // d-waves: same A, B = d_weight in column 0 only
            #pragma unroll
            for (int kc = 0; kc < 16; ++kc) {
                const int k = kc * 32 + kg * 8;
                float4 fa = *(const float4*)(xrow + k);
                float4 fb = *(const float4*)(xrow + k + 4);
                bf16x8 af;
                af[0] = (__bf16)fa.x; af[1] = (__bf16)fa.y; af[2] = (__bf16)fa.z; af[3] = (__bf16)fa.w;
                af[4] = (__bf16)fb.x; af[5] = (__bf16)fb.y; af[6] = (__bf16)fb.z; af[7] = (__bf16)fb.w;
                bf16x8 bd = {};
                if ((l & 15) == 0) bd = *(const bf16x8*)(dwsm + k);
                acc = __builtin_amdgcn_mfma_f32_16x16x32_bf16(af, bd, acc, 0, 0, 0);
            }
            #pragma unroll 8
            for (int kc = 16; kc < 48; ++kc) {
                const int k = kc * 32 + kg * 8;
                bf16x8 af = *(const bf16x8*)(hrow + (k - DIN));
                bf16x8 bd = {};
                if ((l & 15) == 0) bd = *(const bf16x8*)(dwsm + k);
                acc = __builtin_amdgcn_mfma_f32_16x16x32_bf16(af, bd, acc, 0, 0, 0);
            }
            if ((l & 15) == 0) {
                #pragma unroll
                for (int r = 0; r < 4; ++r) {
                    int brow = mT * 16 + kg * 4 + r;
                    float bu = beta * (acc[r] + dbias_s);
                    float sp = (bu > 20.f) ? bu : log1pf(__expf(bu));
                    float dn = sp / beta;
                    dls[brow] = dn;
                    if (wg == 0)
                        __builtin_nontemporal_store(dn, out1 + ((size_t)brow * L_STEPS + t) * 3073 + 3072);
                }
            }
        }
        __syncthreads();

        // ---- phase 4: gate algebra, state update, outputs ----
        if (tid < 256) {
            float gi  = proj[(0 * 8 + j) * 33 + b];
            float gf  = proj[(1 * 8 + j) * 33 + b];
            float gie = proj[(2 * 8 + j) * 33 + b];
            float gfe = proj[(3 * 8 + j) * 33 + b];
            float gz  = proj[(4 * 8 + j) * 33 + b];
            float go  = proj[(5 * 8 + j) * 33 + b];
            float z   = 2.f * gz - 1.f;
            float csn = gf * c_reg + gi * z;
            float cen = gfe * s_ce + gie * z;
            size_t ob = ((size_t)b * L_STEPS + t) * 3073;
            __builtin_nontemporal_store(go,  out1 + ob + c0 + j);
            __builtin_nontemporal_store(csn, out1 + ob + HDIM + c0 + j);
            __builtin_nontemporal_store(cen, out1 + ob + 2 * HDIM + c0 + j);
            s_o = go; s_cs = csn; s_ce = cen;
        }
    }
}

extern "C" void kernel_launch(void* const* d_in, const int* in_sizes, int n_in,
                              void* d_out, int out_size, void* d_ws, size_t ws_size,
                              hipStream_t stream) {
    const float* x        = (const float*)d_in[0];
    const float* tdel     = (const float*)d_in[1];
    const float* o_state  = (const float*)d_in[2];
    const float* cs_state = (const float*)d_in[3];
    const float* ce_state = (const float*)d_in[4];
    const float* d_state  = (const float*)d_in[5];
    const float* weight   = (const float*)d_in[6];
    const float* bias     = (const float*)d_in[7];
    const float* d_weight = (const float*)d_in[8];
    const float* d_bias   = (const float*)d_in[9];
    const float* d_beta   = (const float*)d_in[10];

    float* out0 = (float*)d_out;
    float* out1 = out0 + (size_t)BATCH * L_STEPS * HDIM;

    unsigned int* cnt = (unsigned int*)d_ws;
    __bf16* h0 = (__bf16*)((char*)d_ws + 1024);
    __bf16* h1 = (__bf16*)((char*)d_ws + 1024 + (size_t)BATCH * HDIM * 2);

    hipMemsetAsync(d_ws, 0, 1024, stream);  // barrier counter (re-armed every launch)
    hipFuncSetAttribute((const void*)ctlstm_kernel,
                        hipFuncAttributeMaxDynamicSharedMemorySize, LDS_BYTES);
    ctlstm_kernel<<<NWG, NTHREADS, LDS_BYTES, stream>>>(
        x, tdel, o_state, cs_state, ce_state, d_state,
        weight, bias, d_weight, d_bias, d_beta,
        out0, out1, cnt, h0, h1);
}

// Round 2
// 12069.199 us; speedup vs baseline: 1.0610x; 1.0610x over previous
//
#include <hip/hip_runtime.h>
#include <hip/hip_bf16.h>

// ContTimeLSTM: L=512, B=32, DIN=512, H=1024.
// Persistent kernel: 128 WGs x 512 threads; WG g owns h-columns [8g, 8g+8)
// => 48 weight rows (6 gates x 8 cols) resident in LDS as swizzled bf16.
// Per-step device-wide sync via per-WG epoch flags (no RMW, no L2 wb/inv):
// all cross-WG data moves through relaxed agent-scope (sc1) atomics.

#define L_STEPS 512
#define BATCH   32
#define DIN     512
#define HDIM    1024
#define KDIM    1536     // DIN + HDIM
#define NWG     128
#define CPW     8        // h-cols per WG
#define NLOC    48       // 6*CPW weight rows per WG
#define NTHREADS 512     // 8 waves: 6 gate-tile waves + 2 d-waves
#define WROW_BYTES 3072  // KDIM * 2B

// LDS layout (bytes)
#define LDS_DW    147456                 // after W (48*3072)
#define LDS_PROJ  150528                 // after dw (1536*2)
#define LDS_DLS   156864                 // after proj (48*33*4)
#define LDS_HSTG  156992                 // after dls (32*4)
#define LDS_BYTES 157504                 // + hstage (256*2)

#define FLAG_STRIDE 32                   // uints -> 128 B per flag line
#define WS_FLAGS_BYTES 16384             // 128 * 128 B

typedef __attribute__((ext_vector_type(8))) __bf16 bf16x8;
typedef __attribute__((ext_vector_type(4))) float  f32x4;

struct u64x2 { unsigned long long a, b; };

__device__ __forceinline__ float fsigmoid(float u) { return 1.0f / (1.0f + __expf(-u)); }

extern "C" __global__ void __launch_bounds__(NTHREADS, 1)
ctlstm_kernel(const float* __restrict__ x,
              const float* __restrict__ tdel,
              const float* __restrict__ o_state,
              const float* __restrict__ cs_state,
              const float* __restrict__ ce_state,
              const float* __restrict__ d_state,
              const float* __restrict__ weight,
              const float* __restrict__ bias,
              const float* __restrict__ d_weight,
              const float* __restrict__ d_bias,
              const float* __restrict__ d_beta_p,
              float* __restrict__ out0,
              float* __restrict__ out1,
              unsigned int* __restrict__ flags,
              __bf16* __restrict__ h0,
              __bf16* __restrict__ h1)
{
    extern __shared__ char smem[];
    char*   Wsm  = smem;
    __bf16* dwsm = (__bf16*)(smem + LDS_DW);
    float*  proj = (float*)(smem + LDS_PROJ);
    float*  dls  = (float*)(smem + LDS_DLS);
    __bf16* hstg = (__bf16*)(smem + LDS_HSTG);

    const int tid = threadIdx.x;
    const int wg  = blockIdx.x;
    const int c0  = wg * CPW;

    // ---- startup: stage this WG's 48 weight rows into LDS (bf16, XOR-swizzled) ----
    for (int u = tid; u < NLOC * (KDIM / 4); u += NTHREADS) {
        int rrow = u / (KDIM / 4);
        int k4   = u - rrow * (KDIM / 4);
        int g = rrow >> 3, jj = rrow & 7;
        const float4 f = *(const float4*)(weight + (size_t)(g * HDIM + c0 + jj) * KDIM + k4 * 4);
        __bf16 b0 = (__bf16)f.x, b1 = (__bf16)f.y, b2 = (__bf16)f.z, b3 = (__bf16)f.w;
        unsigned short u0 = __builtin_bit_cast(unsigned short, b0);
        unsigned short u1 = __builtin_bit_cast(unsigned short, b1);
        unsigned short u2 = __builtin_bit_cast(unsigned short, b2);
        unsigned short u3 = __builtin_bit_cast(unsigned short, b3);
        uint2 v;
        v.x = (unsigned)u0 | ((unsigned)u1 << 16);
        v.y = (unsigned)u2 | ((unsigned)u3 << 16);
        unsigned boff = (unsigned)rrow * WROW_BYTES +
                        (((unsigned)(k4 * 8)) ^ (((unsigned)(rrow & 15)) << 4));
        *(uint2*)(Wsm + boff) = v;
    }
    for (int u = tid; u < KDIM; u += NTHREADS) dwsm[u] = (__bf16)d_weight[u];
    if (tid < BATCH) dls[tid] = d_state[tid];

    // ---- per-thread persistent state (threads 0..255 own (b, j)) ----
    float s_o = 0.f, s_cs = 0.f, s_ce = 0.f;
    const int b = tid >> 3, j = tid & 7;
    if (tid < 256) {
        int gi = b * HDIM + c0 + j;
        s_o = o_state[gi]; s_cs = cs_state[gi]; s_ce = ce_state[gi];
    }

    // ---- wave identities ----
    const int wv  = tid >> 6;        // 0..7
    const int l   = tid & 63;
    const int mT  = wv & 1;          // batch-tile
    const int nT  = wv >> 1;         // 0..2 gate tiles; 3 => d-waves
    const int row = mT * 16 + (l & 15);
    const int kg  = l >> 4;
    const int nl  = nT * 16 + (l & 15);   // n-local 0..47 (gate waves)
    float bias_r = 0.f;
    if (wv < 6) bias_r = bias[(nl >> 3) * HDIM + c0 + (nl & 7)];
    const float dbias_s = d_bias[0];
    const float beta    = d_beta_p[0];
    const unsigned xorv  = ((unsigned)(nl & 15)) << 4;
    const unsigned wbase = (unsigned)nl * WROW_BYTES;

    __syncthreads();

    float c_reg = 0.f;
    for (int t = 0; t < L_STEPS; ++t) {
        __bf16* hcur = (t & 1) ? h1 : h0;

        // ---- phase 1: c, h from previous state; stage h slice in LDS ----
        if (tid < 256) {
            float dt = tdel[t * BATCH + b];
            float dv = dls[b];
            float c  = s_cs + (s_ce - s_cs) * __expf(-dv * dt);
            float h  = s_o * (1.f - 2.f / (__expf(2.f * c) + 1.f));  // o * tanh(c)
            c_reg = c;
            hstg[b * CPW + j] = (__bf16)h;
            __builtin_nontemporal_store(h, out0 + ((size_t)b * L_STEPS + t) * HDIM + c0 + j);
        }
        __syncthreads();   // S1: hstg ready

        // ---- publish h slice (wave 0 only, 8-B sc1 stores), then set own flag ----
        if (tid < 64) {
            int bb = tid >> 1, half = tid & 1;
            unsigned long long v = *(const unsigned long long*)(hstg + bb * CPW + half * 4);
            __hip_atomic_store((unsigned long long*)(hcur + (size_t)bb * HDIM + c0 + half * 4),
                               v, __ATOMIC_RELAXED, __HIP_MEMORY_SCOPE_AGENT);
        }
        asm volatile("s_waitcnt vmcnt(0)" ::: "memory");  // per-wave: wave 0's h stores done
        if (tid == 0) {
            __hip_atomic_store(flags + (unsigned)wg * FLAG_STRIDE, (unsigned)(t + 1),
                               __ATOMIC_RELAXED, __HIP_MEMORY_SCOPE_AGENT);
        }

        // ---- x-part MFMA (h-independent) — overlaps the barrier window ----
        const float* xrow = x + ((size_t)t * BATCH + row) * DIN;
        f32x4 acc0 = {0.f, 0.f, 0.f, 0.f};
        f32x4 acc1 = {0.f, 0.f, 0.f, 0.f};

        if (wv < 6) {
            #pragma unroll
            for (int kc = 0; kc < 16; ++kc) {
                const int k = kc * 32 + kg * 8;
                float4 fa = *(const float4*)(xrow + k);
                float4 fb = *(const float4*)(xrow + k + 4);
                bf16x8 af;
                af[0] = (__bf16)fa.x; af[1] = (__bf16)fa.y; af[2] = (__bf16)fa.z; af[3] = (__bf16)fa.w;
                af[4] = (__bf16)fb.x; af[5] = (__bf16)fb.y; af[6] = (__bf16)fb.z; af[7] = (__bf16)fb.w;
                const unsigned koff = (unsigned)(kc * 64 + kg * 16);
                bf16x8 bf = *(const bf16x8*)(Wsm + (wbase + (koff ^ xorv)));
                if (kc & 1) acc1 = __builtin_amdgcn_mfma_f32_16x16x32_bf16(af, bf, acc1, 0, 0, 0);
                else        acc0 = __builtin_amdgcn_mfma_f32_16x16x32_bf16(af, bf, acc0, 0, 0, 0);
            }
        } else {
            #pragma unroll
            for (int kc = 0; kc < 16; ++kc) {
                const int k = kc * 32 + kg * 8;
                float4 fa = *(const float4*)(xrow + k);
                float4 fb = *(const float4*)(xrow + k + 4);
                bf16x8 af;
                af[0] = (__bf16)fa.x; af[1] = (__bf16)fa.y; af[2] = (__bf16)fa.z; af[3] = (__bf16)fa.w;
                af[4] = (__bf16)fb.x; af[5] = (__bf16)fb.y; af[6] = (__bf16)fb.z; af[7] = (__bf16)fb.w;
                bf16x8 bd = {};
                if ((l & 15) == 0) bd = *(const bf16x8*)(dwsm + k);
                if (kc & 1) acc1 = __builtin_amdgcn_mfma_f32_16x16x32_bf16(af, bd, acc1, 0, 0, 0);
                else        acc0 = __builtin_amdgcn_mfma_f32_16x16x32_bf16(af, bd, acc0, 0, 0, 0);
            }
        }

        // ---- wait: all 128 WGs published this step (wave 0 polls, no RMW) ----
        if (tid < 64) {
            const unsigned tgt = (unsigned)(t + 1);
            const unsigned* f0 = flags + (unsigned)l * FLAG_STRIDE;
            const unsigned* f1 = flags + (unsigned)(l + 64) * FLAG_STRIDE;
            for (;;) {
                unsigned a = __hip_atomic_load(f0, __ATOMIC_RELAXED, __HIP_MEMORY_SCOPE_AGENT);
                unsigned c = __hip_atomic_load(f1, __ATOMIC_RELAXED, __HIP_MEMORY_SCOPE_AGENT);
                if (__all((int)(a >= tgt && c >= tgt))) break;
            }
        }
        __syncthreads();   // S2: h complete everywhere

        // ---- h-part MFMA (sc1 8-B loads straight from MALL) ----
        const unsigned long long* hq =
            (const unsigned long long*)(hcur + (size_t)row * HDIM);

        if (wv < 6) {
            #pragma unroll 8
            for (int kc = 16; kc < 48; ++kc) {
                const int k = kc * 32 + kg * 8;
                const int e = (k - DIN) >> 2;
                unsigned long long q0 = __hip_atomic_load(hq + e,     __ATOMIC_RELAXED, __HIP_MEMORY_SCOPE_AGENT);
                unsigned long long q1 = __hip_atomic_load(hq + e + 1, __ATOMIC_RELAXED, __HIP_MEMORY_SCOPE_AGENT);
                u64x2 uu{q0, q1};
                bf16x8 af = __builtin_bit_cast(bf16x8, uu);
                const unsigned koff = (unsigned)(kc * 64 + kg * 16);
                bf16x8 bf = *(const bf16x8*)(Wsm + (wbase + (koff ^ xorv)));
                if (kc & 1) acc1 = __builtin_amdgcn_mfma_f32_16x16x32_bf16(af, bf, acc1, 0, 0, 0);
                else        acc0 = __builtin_amdgcn_mfma_f32_16x16x32_bf16(af, bf, acc0, 0, 0, 0);
            }
            #pragma unroll
            for (int r = 0; r < 4; ++r) {
                float p = fsigmoid(acc0[r] + acc1[r] + bias_r);
                proj[nl * 33 + mT * 16 + kg * 4 + r] = p;
            }
        } else {
            #pragma unroll 8
            for (int kc = 16; kc < 48; ++kc) {
                const int k = kc * 32 + kg * 8;
                const int e = (k - DIN) >> 2;
                unsigned long long q0 = __hip_atomic_load(hq + e,     __ATOMIC_RELAXED, __HIP_MEMORY_SCOPE_AGENT);
                unsigned long long q1 = __hip_atomic_load(hq + e + 1, __ATOMIC_RELAXED, __HIP_MEMORY_SCOPE_AGENT);
                u64x2 uu{q0, q1};
                bf16x8 af = __builtin_bit_cast(bf16x8, uu);
                bf16x8 bd = {};
                if ((l & 15) == 0) bd = *(const bf16x8*)(dwsm + k);
                if (kc & 1) acc1 = __builtin_amdgcn_mfma_f32_16x16x32_bf16(af, bd, acc1, 0, 0, 0);
                else        acc0 = __builtin_amdgcn_mfma_f32_16x16x32_bf16(af, bd, acc0, 0, 0, 0);
            }
            if ((l & 15) == 0) {
                #pragma unroll
                for (int r = 0; r < 4; ++r) {
                    int brow = mT * 16 + kg * 4 + r;
                    float bu = beta * (acc0[r] + acc1[r] + dbias_s);
                    float sp = (bu > 20.f) ? bu : log1pf(__expf(bu));
                    float dn = sp / beta;
                    dls[brow] = dn;
                    if (wg == 0)
                        __builtin_nontemporal_store(dn, out1 + ((size_t)brow * L_STEPS + t) * 3073 + 3072);
                }
            }
        }
        __syncthreads();   // S3: proj + dls ready

        // ---- phase 4: gate algebra, state update, outputs ----
        if (tid < 256) {
            float gi  = proj[(0 * 8 + j) * 33 + b];
            float gf  = proj[(1 * 8 + j) * 33 + b];
            float gie = proj[(2 * 8 + j) * 33 + b];
            float gfe = proj[(3 * 8 + j) * 33 + b];
            float gz  = proj[(4 * 8 + j) * 33 + b];
            float go  = proj[(5 * 8 + j) * 33 + b];
            float z   = 2.f * gz - 1.f;
            float csn = gf * c_reg + gi * z;
            float cen = gfe * s_ce + gie * z;
            size_t ob = ((size_t)b * L_STEPS + t) * 3073;
            __builtin_nontemporal_store(go,  out1 + ob + c0 + j);
            __builtin_nontemporal_store(csn, out1 + ob + HDIM + c0 + j);
            __builtin_nontemporal_store(cen, out1 + ob + 2 * HDIM + c0 + j);
            s_o = go; s_cs = csn; s_ce = cen;
        }
    }
}

extern "C" void kernel_launch(void* const* d_in, const int* in_sizes, int n_in,
                              void* d_out, int out_size, void* d_ws, size_t ws_size,
                              hipStream_t stream) {
    const float* x        = (const float*)d_in[0];
    const float* tdel     = (const float*)d_in[1];
    const float* o_state  = (const float*)d_in[2];
    const float* cs_state = (const float*)d_in[3];
    const float* ce_state = (const float*)d_in[4];
    const float* d_state  = (const float*)d_in[5];
    const float* weight   = (const float*)d_in[6];
    const float* bias     = (const float*)d_in[7];
    const float* d_weight = (const float*)d_in[8];
    const float* d_bias   = (const float*)d_in[9];
    const float* d_beta   = (const float*)d_in[10];

    float* out0 = (float*)d_out;
    float* out1 = out0 + (size_t)BATCH * L_STEPS * HDIM;

    unsigned int* flags = (unsigned int*)d_ws;
    __bf16* h0 = (__bf16*)((char*)d_ws + WS_FLAGS_BYTES);
    __bf16* h1 = (__bf16*)((char*)d_ws + WS_FLAGS_BYTES + (size_t)BATCH * HDIM * 2);

    hipMemsetAsync(d_ws, 0, WS_FLAGS_BYTES, stream);  // re-arm flags every launch
    hipFuncSetAttribute((const void*)ctlstm_kernel,
                        hipFuncAttributeMaxDynamicSharedMemorySize, LDS_BYTES);
    ctlstm_kernel<<<NWG, NTHREADS, LDS_BYTES, stream>>>(
        x, tdel, o_state, cs_state, ce_state, d_state,
        weight, bias, d_weight, d_bias, d_beta,
        out0, out1, flags, h0, h1);
}

// Round 3
// 11557.532 us; speedup vs baseline: 1.1080x; 1.0443x over previous
//
#include <hip/hip_runtime.h>
#include <hip/hip_bf16.h>

// ContTimeLSTM: L=512, B=32, DIN=512, H=1024.
// Persistent kernel: 128 WGs x 512 threads; WG g owns h-columns [8g, 8g+8)
// => 48 weight rows (6 gates x 8 cols) resident in LDS as swizzled bf16.
// Per-step device-wide sync: packed ushort epoch flags (2 cache lines total).
// All cross-WG data moves through relaxed agent-scope (sc1) accesses; the
// only ordering primitive is a wave-0 vmcnt(0) between h-publish and flag.

#define L_STEPS 512
#define BATCH   32
#define DIN     512
#define HDIM    1024
#define KDIM    1536     // DIN + HDIM
#define NWG     128
#define CPW     8        // h-cols per WG
#define NLOC    48       // 6*CPW weight rows per WG
#define NTHREADS 512     // 8 waves: 6 gate-tile waves + 2 d-waves
#define WROW_BYTES 3072  // KDIM * 2B

// LDS layout (bytes)
#define LDS_DW    147456                 // after W (48*3072)
#define LDS_PROJ  150528                 // after dw (1536*2)
#define LDS_DLS   156864                 // after proj (48*33*4)
#define LDS_HSTG  156992                 // after dls (32*4)
#define LDS_BYTES 157504                 // + hstage (256*2)

#define WS_FLAGS_BYTES 1024              // flags: 128 ushorts (256 B) padded

typedef __attribute__((ext_vector_type(8))) __bf16 bf16x8;
typedef __attribute__((ext_vector_type(4))) float  f32x4;

struct u64x2 { unsigned long long a, b; };

__device__ __forceinline__ float fsigmoid(float u) { return 1.0f / (1.0f + __expf(-u)); }

extern "C" __global__ void __launch_bounds__(NTHREADS, 1)
ctlstm_kernel(const float* __restrict__ x,
              const float* __restrict__ tdel,
              const float* __restrict__ o_state,
              const float* __restrict__ cs_state,
              const float* __restrict__ ce_state,
              const float* __restrict__ d_state,
              const float* __restrict__ weight,
              const float* __restrict__ bias,
              const float* __restrict__ d_weight,
              const float* __restrict__ d_bias,
              const float* __restrict__ d_beta_p,
              float* __restrict__ out0,
              float* __restrict__ out1,
              unsigned short* __restrict__ flags,
              __bf16* __restrict__ h0,
              __bf16* __restrict__ h1)
{
    extern __shared__ char smem[];
    char*   Wsm  = smem;
    __bf16* dwsm = (__bf16*)(smem + LDS_DW);
    float*  proj = (float*)(smem + LDS_PROJ);
    float*  dls  = (float*)(smem + LDS_DLS);
    __bf16* hstg = (__bf16*)(smem + LDS_HSTG);

    const int tid = threadIdx.x;
    const int wg  = blockIdx.x;
    const int c0  = wg * CPW;

    // ---- startup: stage this WG's 48 weight rows into LDS (bf16, XOR-swizzled) ----
    for (int u = tid; u < NLOC * (KDIM / 4); u += NTHREADS) {
        int rrow = u / (KDIM / 4);
        int k4   = u - rrow * (KDIM / 4);
        int g = rrow >> 3, jj = rrow & 7;
        const float4 f = *(const float4*)(weight + (size_t)(g * HDIM + c0 + jj) * KDIM + k4 * 4);
        __bf16 b0 = (__bf16)f.x, b1 = (__bf16)f.y, b2 = (__bf16)f.z, b3 = (__bf16)f.w;
        unsigned short u0 = __builtin_bit_cast(unsigned short, b0);
        unsigned short u1 = __builtin_bit_cast(unsigned short, b1);
        unsigned short u2 = __builtin_bit_cast(unsigned short, b2);
        unsigned short u3 = __builtin_bit_cast(unsigned short, b3);
        uint2 v;
        v.x = (unsigned)u0 | ((unsigned)u1 << 16);
        v.y = (unsigned)u2 | ((unsigned)u3 << 16);
        unsigned boff = (unsigned)rrow * WROW_BYTES +
                        (((unsigned)(k4 * 8)) ^ (((unsigned)(rrow & 15)) << 4));
        *(uint2*)(Wsm + boff) = v;
    }
    for (int u = tid; u < KDIM; u += NTHREADS) dwsm[u] = (__bf16)d_weight[u];
    if (tid < BATCH) dls[tid] = d_state[tid];

    // ---- per-thread persistent state (threads 0..255 own (b, j)) ----
    float s_o = 0.f, s_cs = 0.f, s_ce = 0.f, dt_cur = 0.f;
    const int b = tid >> 3, j = tid & 7;
    if (tid < 256) {
        int gi = b * HDIM + c0 + j;
        s_o = o_state[gi]; s_cs = cs_state[gi]; s_ce = ce_state[gi];
        dt_cur = tdel[b];               // t = 0 prefetch
    }

    // ---- wave identities ----
    const int wv  = tid >> 6;        // 0..7
    const int l   = tid & 63;
    const int mT  = wv & 1;          // batch-tile
    const int nT  = wv >> 1;         // 0..2 gate tiles; 3 => d-waves
    const int row = mT * 16 + (l & 15);
    const int kg  = l >> 4;
    const int nl  = nT * 16 + (l & 15);   // n-local 0..47 (gate waves)
    float bias_r = 0.f;
    if (wv < 6) bias_r = bias[(nl >> 3) * HDIM + c0 + (nl & 7)];
    const float dbias_s = d_bias[0];
    const float beta    = d_beta_p[0];
    const unsigned xorv  = ((unsigned)(nl & 15)) << 4;
    const unsigned wbase = (unsigned)nl * WROW_BYTES;

    __syncthreads();

    float c_reg = 0.f;
    for (int t = 0; t < L_STEPS; ++t) {
        __bf16* hcur = (t & 1) ? h1 : h0;

        // ---- phase 1: c, h from previous state; stage h slice in LDS ----
        float h_reg = 0.f;
        if (tid < 256) {
            float dv = dls[b];
            float c  = s_cs + (s_ce - s_cs) * __expf(-dv * dt_cur);
            h_reg    = s_o * (1.f - 2.f / (__expf(2.f * c) + 1.f));  // o * tanh(c)
            c_reg = c;
            hstg[b * CPW + j] = (__bf16)h_reg;
        }
        __syncthreads();   // S1: hstg ready

        // ---- wave 0: publish h (8-B sc1 stores), ack, set own epoch flag ----
        if (tid < 64) {
            int bb = tid >> 1, half = tid & 1;
            unsigned long long v = *(const unsigned long long*)(hstg + bb * CPW + half * 4);
            __hip_atomic_store((unsigned long long*)(hcur + (size_t)bb * HDIM + c0 + half * 4),
                               v, __ATOMIC_RELAXED, __HIP_MEMORY_SCOPE_AGENT);
            asm volatile("s_waitcnt vmcnt(0)" ::: "memory");  // h stores at MALL
            if (tid == 0)
                __hip_atomic_store(flags + wg, (unsigned short)(t + 1),
                                   __ATOMIC_RELAXED, __HIP_MEMORY_SCOPE_AGENT);
            asm volatile("" ::: "memory");                    // don't sink flag store
        }

        // ---- off-critical-path work: out0 store + tdel prefetch ----
        float dt_nxt = 0.f;
        if (tid < 256) {
            __builtin_nontemporal_store(h_reg, out0 + ((size_t)b * L_STEPS + t) * HDIM + c0 + j);
            int tn = (t + 1 < L_STEPS) ? (t + 1) : (L_STEPS - 1);
            dt_nxt = tdel[tn * BATCH + b];
        }

        // ---- x-part MFMA (h-independent) — overlaps the barrier window ----
        const float* xrow = x + ((size_t)t * BATCH + row) * DIN;
        f32x4 acc0 = {0.f, 0.f, 0.f, 0.f};
        f32x4 acc1 = {0.f, 0.f, 0.f, 0.f};

        if (wv < 6) {
            #pragma unroll
            for (int kc = 0; kc < 16; ++kc) {
                const int k = kc * 32 + kg * 8;
                float4 fa = *(const float4*)(xrow + k);
                float4 fb = *(const float4*)(xrow + k + 4);
                bf16x8 af;
                af[0] = (__bf16)fa.x; af[1] = (__bf16)fa.y; af[2] = (__bf16)fa.z; af[3] = (__bf16)fa.w;
                af[4] = (__bf16)fb.x; af[5] = (__bf16)fb.y; af[6] = (__bf16)fb.z; af[7] = (__bf16)fb.w;
                const unsigned koff = (unsigned)(kc * 64 + kg * 16);
                bf16x8 bf = *(const bf16x8*)(Wsm + (wbase + (koff ^ xorv)));
                if (kc & 1) acc1 = __builtin_amdgcn_mfma_f32_16x16x32_bf16(af, bf, acc1, 0, 0, 0);
                else        acc0 = __builtin_amdgcn_mfma_f32_16x16x32_bf16(af, bf, acc0, 0, 0, 0);
            }
        } else {
            #pragma unroll
            for (int kc = 0; kc < 16; ++kc) {
                const int k = kc * 32 + kg * 8;
                float4 fa = *(const float4*)(xrow + k);
                float4 fb = *(const float4*)(xrow + k + 4);
                bf16x8 af;
                af[0] = (__bf16)fa.x; af[1] = (__bf16)fa.y; af[2] = (__bf16)fa.z; af[3] = (__bf16)fa.w;
                af[4] = (__bf16)fb.x; af[5] = (__bf16)fb.y; af[6] = (__bf16)fb.z; af[7] = (__bf16)fb.w;
                bf16x8 bd = {};
                if ((l & 15) == 0) bd = *(const bf16x8*)(dwsm + k);
                if (kc & 1) acc1 = __builtin_amdgcn_mfma_f32_16x16x32_bf16(af, bd, acc1, 0, 0, 0);
                else        acc0 = __builtin_amdgcn_mfma_f32_16x16x32_bf16(af, bd, acc0, 0, 0, 0);
            }
        }

        // ---- wait: all 128 WGs published (wave 0 reads 2 cache lines/iter) ----
        if (tid < 64) {
            const unsigned tgt = (unsigned)(t + 1);
            const unsigned* fl = (const unsigned*)flags + l;   // 64 dwords = 128 ushorts
            for (;;) {
                unsigned v = __hip_atomic_load(fl, __ATOMIC_RELAXED, __HIP_MEMORY_SCOPE_AGENT);
                if (__all((int)((v & 0xFFFFu) >= tgt && (v >> 16) >= tgt))) break;
            }
        }
        __syncthreads();   // S2: h complete everywhere

        // ---- h-part MFMA (sc1 8-B loads straight from MALL) ----
        const unsigned long long* hq =
            (const unsigned long long*)(hcur + (size_t)row * HDIM);

        if (wv < 6) {
            #pragma unroll 8
            for (int kc = 16; kc < 48; ++kc) {
                const int k = kc * 32 + kg * 8;
                const int e = (k - DIN) >> 2;
                unsigned long long q0 = __hip_atomic_load(hq + e,     __ATOMIC_RELAXED, __HIP_MEMORY_SCOPE_AGENT);
                unsigned long long q1 = __hip_atomic_load(hq + e + 1, __ATOMIC_RELAXED, __HIP_MEMORY_SCOPE_AGENT);
                u64x2 uu{q0, q1};
                bf16x8 af = __builtin_bit_cast(bf16x8, uu);
                const unsigned koff = (unsigned)(kc * 64 + kg * 16);
                bf16x8 bf = *(const bf16x8*)(Wsm + (wbase + (koff ^ xorv)));
                if (kc & 1) acc1 = __builtin_amdgcn_mfma_f32_16x16x32_bf16(af, bf, acc1, 0, 0, 0);
                else        acc0 = __builtin_amdgcn_mfma_f32_16x16x32_bf16(af, bf, acc0, 0, 0, 0);
            }
            #pragma unroll
            for (int r = 0; r < 4; ++r) {
                float p = fsigmoid(acc0[r] + acc1[r] + bias_r);
                proj[nl * 33 + mT * 16 + kg * 4 + r] = p;
            }
        } else {
            #pragma unroll 8
            for (int kc = 16; kc < 48; ++kc) {
                const int k = kc * 32 + kg * 8;
                const int e = (k - DIN) >> 2;
                unsigned long long q0 = __hip_atomic_load(hq + e,     __ATOMIC_RELAXED, __HIP_MEMORY_SCOPE_AGENT);
                unsigned long long q1 = __hip_atomic_load(hq + e + 1, __ATOMIC_RELAXED, __HIP_MEMORY_SCOPE_AGENT);
                u64x2 uu{q0, q1};
                bf16x8 af = __builtin_bit_cast(bf16x8, uu);
                bf16x8 bd = {};
                if ((l & 15) == 0) bd = *(const bf16x8*)(dwsm + k);
                if (kc & 1) acc1 = __builtin_amdgcn_mfma_f32_16x16x32_bf16(af, bd, acc1, 0, 0, 0);
                else        acc0 = __builtin_amdgcn_mfma_f32_16x16x32_bf16(af, bd, acc0, 0, 0, 0);
            }
            if ((l & 15) == 0) {
                #pragma unroll
                for (int r = 0; r < 4; ++r) {
                    int brow = mT * 16 + kg * 4 + r;
                    float bu = beta * (acc0[r] + acc1[r] + dbias_s);
                    // stable branch-free softplus: max(x,0) + log(1+exp(-|x|))
                    float sp = fmaxf(bu, 0.f) + __logf(1.f + __expf(-fabsf(bu)));
                    float dn = sp / beta;
                    dls[brow] = dn;
                    if (wg == 0)
                        __builtin_nontemporal_store(dn, out1 + ((size_t)brow * L_STEPS + t) * 3073 + 3072);
                }
            }
        }
        __syncthreads();   // S3: proj + dls ready

        // ---- phase 4: gate algebra, state update, outputs ----
        if (tid < 256) {
            float gi  = proj[(0 * 8 + j) * 33 + b];
            float gf  = proj[(1 * 8 + j) * 33 + b];
            float gie = proj[(2 * 8 + j) * 33 + b];
            float gfe = proj[(3 * 8 + j) * 33 + b];
            float gz  = proj[(4 * 8 + j) * 33 + b];
            float go  = proj[(5 * 8 + j) * 33 + b];
            float z   = 2.f * gz - 1.f;
            float csn = gf * c_reg + gi * z;
            float cen = gfe * s_ce + gie * z;
            size_t ob = ((size_t)b * L_STEPS + t) * 3073;
            __builtin_nontemporal_store(go,  out1 + ob + c0 + j);
            __builtin_nontemporal_store(csn, out1 + ob + HDIM + c0 + j);
            __builtin_nontemporal_store(cen, out1 + ob + 2 * HDIM + c0 + j);
            s_o = go; s_cs = csn; s_ce = cen;
        }
        dt_cur = dt_nxt;
    }
}

extern "C" void kernel_launch(void* const* d_in, const int* in_sizes, int n_in,
                              void* d_out, int out_size, void* d_ws, size_t ws_size,
                              hipStream_t stream) {
    const float* x        = (const float*)d_in[0];
    const float* tdel     = (const float*)d_in[1];
    const float* o_state  = (const float*)d_in[2];
    const float* cs_state = (const float*)d_in[3];
    const float* ce_state = (const float*)d_in[4];
    const float* d_state  = (const float*)d_in[5];
    const float* weight   = (const float*)d_in[6];
    const float* bias     = (const float*)d_in[7];
    const float* d_weight = (const float*)d_in[8];
    const float* d_bias   = (const float*)d_in[9];
    const float* d_beta   = (const float*)d_in[10];

    float* out0 = (float*)d_out;
    float* out1 = out0 + (size_t)BATCH * L_STEPS * HDIM;

    unsigned short* flags = (unsigned short*)d_ws;
    __bf16* h0 = (__bf16*)((char*)d_ws + WS_FLAGS_BYTES);
    __bf16* h1 = (__bf16*)((char*)d_ws + WS_FLAGS_BYTES + (size_t)BATCH * HDIM * 2);

    hipMemsetAsync(d_ws, 0, WS_FLAGS_BYTES, stream);  // re-arm flags every launch
    hipFuncSetAttribute((const void*)ctlstm_kernel,
                        hipFuncAttributeMaxDynamicSharedMemorySize, LDS_BYTES);
    ctlstm_kernel<<<NWG, NTHREADS, LDS_BYTES, stream>>>(
        x, tdel, o_state, cs_state, ce_state, d_state,
        weight, bias, d_weight, d_bias, d_beta,
        out0, out1, flags, h0, h1);
}

// Round 4
// 3265.311 us; speedup vs baseline: 3.9216x; 3.5395x over previous
//
#include <hip/hip_runtime.h>
#include <hip/hip_bf16.h>

// ContTimeLSTM: L=512, B=32, DIN=512, H=1024.
// Persistent kernel: 128 WGs x 256 threads (4 waves, 1/SIMD).
// WG g owns h-columns [8g, 8g+8) => 48 projection rows.
// Weights live in REGISTERS (48 x bf16x8 per lane). LDS holds:
//   - double-buffered x panel (bf16, swizzled)   2 x 32 KB
//   - h panel staged once per step (bf16, swz)   64 KB
//   - proj / dls / hstg scratch                  ~7 KB
// Cross-WG h exchange via relaxed agent-scope (sc1) 8-B accesses; packed
// ushort epoch flags (2 cache lines) for the per-step device-wide sync.

#define L_STEPS 512
#define BATCH   32
#define DIN     512
#define HDIM    1024
#define KDIM    1536
#define NWG     128
#define CPW     8
#define NTHREADS 256

// LDS layout (bytes)
#define LDS_XB0   0        // [32][512] bf16 swizzled  (32 KB)
#define LDS_XB1   32768
#define LDS_HB    65536    // [32][1024] bf16 swizzled (64 KB)
#define LDS_PROJ  131072   // 48*33 floats (6336 B)
#define LDS_DLS   137408   // 32 floats
#define LDS_HSTG  137536   // 256 bf16 (512 B)
#define LDS_BYTES 138048

#define WS_FLAGS_BYTES 1024

typedef __attribute__((ext_vector_type(8))) __bf16 bf16x8;
typedef __attribute__((ext_vector_type(4))) float  f32x4;

__device__ __forceinline__ float fsigmoid(float u) { return 1.0f / (1.0f + __expf(-u)); }

__device__ __forceinline__ bf16x8 pack8(float4 fa, float4 fb) {
    bf16x8 v;
    v[0] = (__bf16)fa.x; v[1] = (__bf16)fa.y; v[2] = (__bf16)fa.z; v[3] = (__bf16)fa.w;
    v[4] = (__bf16)fb.x; v[5] = (__bf16)fb.y; v[6] = (__bf16)fb.z; v[7] = (__bf16)fb.w;
    return v;
}

__device__ __forceinline__ uint2 pack4(float4 f) {
    __bf16 b0 = (__bf16)f.x, b1 = (__bf16)f.y, b2 = (__bf16)f.z, b3 = (__bf16)f.w;
    unsigned short u0 = __builtin_bit_cast(unsigned short, b0);
    unsigned short u1 = __builtin_bit_cast(unsigned short, b1);
    unsigned short u2 = __builtin_bit_cast(unsigned short, b2);
    unsigned short u3 = __builtin_bit_cast(unsigned short, b3);
    uint2 v;
    v.x = (unsigned)u0 | ((unsigned)u1 << 16);
    v.y = (unsigned)u2 | ((unsigned)u3 << 16);
    return v;
}

extern "C" __global__ void __launch_bounds__(NTHREADS, 1)
ctlstm_kernel(const float* __restrict__ x,
              const float* __restrict__ tdel,
              const float* __restrict__ o_state,
              const float* __restrict__ cs_state,
              const float* __restrict__ ce_state,
              const float* __restrict__ d_state,
              const float* __restrict__ weight,
              const float* __restrict__ bias,
              const float* __restrict__ d_weight,
              const float* __restrict__ d_bias,
              const float* __restrict__ d_beta_p,
              float* __restrict__ out0,
              float* __restrict__ out1,
              unsigned short* __restrict__ flags,
              __bf16* __restrict__ h0,
              __bf16* __restrict__ h1)
{
    extern __shared__ char smem[];
    float*  proj = (float*)(smem + LDS_PROJ);
    float*  dls  = (float*)(smem + LDS_DLS);
    __bf16* hstg = (__bf16*)(smem + LDS_HSTG);
    char*   hbp  = smem + LDS_HB;

    const int tid = threadIdx.x;
    const int wg  = blockIdx.x;
    const int c0  = wg * CPW;

    const int wv = tid >> 6;        // 0..3: waves 0-2 gates, wave 3 = d
    const int l  = tid & 63;
    const int lr = l & 15;          // tile row/col index
    const int lk = l >> 4;          // k-group 0..3

    // ---- per-thread persistent state (all 256 threads own (b, j)) ----
    const int b = tid >> 3, j = tid & 7;
    float s_o, s_cs, s_ce, dt_cur;
    {
        int gi = b * HDIM + c0 + j;
        s_o = o_state[gi]; s_cs = cs_state[gi]; s_ce = ce_state[gi];
        dt_cur = tdel[b];
    }
    if (tid < BATCH) dls[tid] = d_state[tid];

    // ---- startup: weights into registers (48 x bf16x8 per lane) ----
    bf16x8 Bx[16], Bh[32];
    float bias_r = 0.f;
    {
        const float* wsrc;
        bool valid = true;
        if (wv < 3) {
            int n = wv * 16 + lr, g = n >> 3, jj = n & 7;
            wsrc = weight + (size_t)(g * HDIM + c0 + jj) * KDIM;
            bias_r = bias[g * HDIM + c0 + jj];
        } else {
            wsrc = d_weight;
            valid = (lr == 0);
        }
        #pragma unroll
        for (int kc = 0; kc < 48; ++kc) {
            bf16x8 v = {};
            if (valid) {
                float4 fa = *(const float4*)(wsrc + kc * 32 + lk * 8);
                float4 fb = *(const float4*)(wsrc + kc * 32 + lk * 8 + 4);
                v = pack8(fa, fb);
            }
            if (kc < 16) Bx[kc] = v; else Bh[kc - 16] = v;
        }
    }
    const float dbias_s = d_bias[0];
    const float beta    = d_beta_p[0];

    // ---- startup: stage x panel 0 into xb[0] (bf16, swizzled) ----
    {
        const float* xp = x;   // panel [32][512]
        #pragma unroll
        for (int r = 0; r < 16; ++r) {
            float4 f = *(const float4*)(xp + r * 1024 + tid * 4);
            int fo  = r * 1024 + tid * 4;
            int row = fo >> 9;
            int col = fo & 511;
            unsigned ba = (unsigned)(row * 1024 + col * 2);
            ba ^= ((unsigned)(row & 7)) << 4;
            *(uint2*)(smem + LDS_XB0 + ba) = pack4(f);
        }
    }
    __syncthreads();

    float c_reg = 0.f;
    for (int t = 0; t < L_STEPS; ++t) {
        __bf16* hcur = (t & 1) ? h1 : h0;
        const char* hcb = (const char*)hcur;
        char* xcur = smem + ((t & 1) ? LDS_XB1 : LDS_XB0);
        char* xnxt = smem + ((t & 1) ? LDS_XB0 : LDS_XB1);

        // ---- A: phase 1 — c, h from previous state; stage h slice in LDS ----
        float dv = dls[b];
        float c  = s_cs + (s_ce - s_cs) * __expf(-dv * dt_cur);
        float h_reg = s_o * (1.f - 2.f / (__expf(2.f * c) + 1.f));  // o*tanh(c)
        c_reg = c;
        hstg[b * CPW + j] = (__bf16)h_reg;
        __syncthreads();   // S1

        // ---- B: wave 0 publishes h slice (8-B sc1 stores), ack, flag ----
        if (tid < 64) {
            int bb = tid >> 1, half = tid & 1;
            unsigned long long v = *(const unsigned long long*)(hstg + bb * CPW + half * 4);
            __hip_atomic_store((unsigned long long*)(hcur + (size_t)bb * HDIM + c0 + half * 4),
                               v, __ATOMIC_RELAXED, __HIP_MEMORY_SCOPE_AGENT);
            asm volatile("s_waitcnt vmcnt(0)" ::: "memory");
            if (tid == 0)
                __hip_atomic_store(flags + wg, (unsigned short)(t + 1),
                                   __ATOMIC_RELAXED, __HIP_MEMORY_SCOPE_AGENT);
            asm volatile("" ::: "memory");
        }

        // ---- C: off-path — out0 store + tdel prefetch ----
        __builtin_nontemporal_store(h_reg, out0 + ((size_t)b * L_STEPS + t) * HDIM + c0 + j);
        int tn = (t + 1 < L_STEPS) ? (t + 1) : (L_STEPS - 1);
        float dt_nxt = tdel[tn * BATCH + b];

        // ---- D: issue next x panel loads (held in regs through the step) ----
        float4 xr[16];
        {
            const float* xp = x + (size_t)tn * BATCH * DIN;
            #pragma unroll
            for (int r = 0; r < 16; ++r)
                xr[r] = *(const float4*)(xp + r * 1024 + tid * 4);
        }

        // ---- E: x-part MFMA from LDS x tile (overlaps barrier window) ----
        f32x4 acc0 = {0.f, 0.f, 0.f, 0.f};
        f32x4 acc1 = {0.f, 0.f, 0.f, 0.f};
        {
            const unsigned swz = ((unsigned)(lr & 7)) << 4;
            #pragma unroll
            for (int kc = 0; kc < 16; ++kc) {
                unsigned cb = (unsigned)(kc * 64 + lk * 16);
                bf16x8 a0 = *(const bf16x8*)(xcur + lr * 1024 + (cb ^ swz));
                bf16x8 a1 = *(const bf16x8*)(xcur + (16 + lr) * 1024 + (cb ^ swz));
                acc0 = __builtin_amdgcn_mfma_f32_16x16x32_bf16(a0, Bx[kc], acc0, 0, 0, 0);
                acc1 = __builtin_amdgcn_mfma_f32_16x16x32_bf16(a1, Bx[kc], acc1, 0, 0, 0);
            }
        }

        // ---- F: wave 0 polls packed flags (2 cache lines) ----
        if (tid < 64) {
            const unsigned tgt = (unsigned)(t + 1);
            const unsigned* fl = (const unsigned*)flags + l;
            for (;;) {
                unsigned v = __hip_atomic_load(fl, __ATOMIC_RELAXED, __HIP_MEMORY_SCOPE_AGENT);
                if (__all((int)((v & 0xFFFFu) >= tgt && (v >> 16) >= tgt))) break;
            }
        }
        __syncthreads();   // S2: all h published

        // ---- G+I: cooperative h stage — 32 batched 8-B sc1 loads/lane → LDS ----
        {
            unsigned long long q[32];
            #pragma unroll
            for (int r = 0; r < 16; ++r) {
                unsigned g = (unsigned)(r * 4096 + tid * 16);
                q[2 * r]     = __hip_atomic_load((const unsigned long long*)(hcb + g),
                                                 __ATOMIC_RELAXED, __HIP_MEMORY_SCOPE_AGENT);
                q[2 * r + 1] = __hip_atomic_load((const unsigned long long*)(hcb + g + 8),
                                                 __ATOMIC_RELAXED, __HIP_MEMORY_SCOPE_AGENT);
            }
            #pragma unroll
            for (int r = 0; r < 16; ++r) {
                unsigned g   = (unsigned)(r * 4096 + tid * 16);
                unsigned row = g >> 11;
                unsigned cb  = g & 2047;
                unsigned ba  = row * 2048 + (cb ^ (((unsigned)(row & 7)) << 4));
                ulonglong2 w; w.x = q[2 * r]; w.y = q[2 * r + 1];
                *(ulonglong2*)(hbp + ba) = w;
            }
        }
        __syncthreads();   // S_stage: h tile ready

        // ---- H: convert + write next x panel (off critical path) ----
        #pragma unroll
        for (int r = 0; r < 16; ++r) {
            int fo  = r * 1024 + tid * 4;
            int row = fo >> 9;
            int col = fo & 511;
            unsigned ba = (unsigned)(row * 1024 + col * 2);
            ba ^= ((unsigned)(row & 7)) << 4;
            *(uint2*)(xnxt + ba) = pack4(xr[r]);
        }

        // ---- J: h-part MFMA from LDS h tile ----
        {
            const unsigned swz = ((unsigned)(lr & 7)) << 4;
            #pragma unroll
            for (int kc = 0; kc < 32; ++kc) {
                unsigned cb = (unsigned)(kc * 64 + lk * 16);
                bf16x8 a0 = *(const bf16x8*)(hbp + lr * 2048 + (cb ^ swz));
                bf16x8 a1 = *(const bf16x8*)(hbp + (16 + lr) * 2048 + (cb ^ swz));
                acc0 = __builtin_amdgcn_mfma_f32_16x16x32_bf16(a0, Bh[kc], acc0, 0, 0, 0);
                acc1 = __builtin_amdgcn_mfma_f32_16x16x32_bf16(a1, Bh[kc], acc1, 0, 0, 0);
            }
        }

        if (wv < 3) {
            const int n = wv * 16 + lr;
            #pragma unroll
            for (int r = 0; r < 4; ++r) {
                float p0 = fsigmoid(acc0[r] + bias_r);
                float p1 = fsigmoid(acc1[r] + bias_r);
                proj[n * 33 + lk * 4 + r]      = p0;
                proj[n * 33 + 16 + lk * 4 + r] = p1;
            }
        } else if (lr == 0) {
            #pragma unroll
            for (int r = 0; r < 4; ++r) {
                int r0 = lk * 4 + r, r1 = 16 + lk * 4 + r;
                float bu0 = beta * (acc0[r] + dbias_s);
                float bu1 = beta * (acc1[r] + dbias_s);
                float sp0 = fmaxf(bu0, 0.f) + __logf(1.f + __expf(-fabsf(bu0)));
                float sp1 = fmaxf(bu1, 0.f) + __logf(1.f + __expf(-fabsf(bu1)));
                float dn0 = sp0 / beta, dn1 = sp1 / beta;
                dls[r0] = dn0; dls[r1] = dn1;
                if (wg == 0) {
                    __builtin_nontemporal_store(dn0, out1 + ((size_t)r0 * L_STEPS + t) * 3073 + 3072);
                    __builtin_nontemporal_store(dn1, out1 + ((size_t)r1 * L_STEPS + t) * 3073 + 3072);
                }
            }
        }
        __syncthreads();   // S3: proj + dls ready

        // ---- K: phase 4 — gate algebra, state update, outputs ----
        {
            float gi  = proj[(0 * 8 + j) * 33 + b];
            float gf  = proj[(1 * 8 + j) * 33 + b];
            float gie = proj[(2 * 8 + j) * 33 + b];
            float gfe = proj[(3 * 8 + j) * 33 + b];
            float gz  = proj[(4 * 8 + j) * 33 + b];
            float go  = proj[(5 * 8 + j) * 33 + b];
            float z   = 2.f * gz - 1.f;
            float csn = gf * c_reg + gi * z;
            float cen = gfe * s_ce + gie * z;
            size_t ob = ((size_t)b * L_STEPS + t) * 3073;
            __builtin_nontemporal_store(go,  out1 + ob + c0 + j);
            __builtin_nontemporal_store(csn, out1 + ob + HDIM + c0 + j);
            __builtin_nontemporal_store(cen, out1 + ob + 2 * HDIM + c0 + j);
            s_o = go; s_cs = csn; s_ce = cen;
        }
        dt_cur = dt_nxt;
    }
}

extern "C" void kernel_launch(void* const* d_in, const int* in_sizes, int n_in,
                              void* d_out, int out_size, void* d_ws, size_t ws_size,
                              hipStream_t stream) {
    const float* x        = (const float*)d_in[0];
    const float* tdel     = (const float*)d_in[1];
    const float* o_state  = (const float*)d_in[2];
    const float* cs_state = (const float*)d_in[3];
    const float* ce_state = (const float*)d_in[4];
    const float* d_state  = (const float*)d_in[5];
    const float* weight   = (const float*)d_in[6];
    const float* bias     = (const float*)d_in[7];
    const float* d_weight = (const float*)d_in[8];
    const float* d_bias   = (const float*)d_in[9];
    const float* d_beta   = (const float*)d_in[10];

    float* out0 = (float*)d_out;
    float* out1 = out0 + (size_t)BATCH * L_STEPS * HDIM;

    unsigned short* flags = (unsigned short*)d_ws;
    __bf16* h0 = (__bf16*)((char*)d_ws + WS_FLAGS_BYTES);
    __bf16* h1 = (__bf16*)((char*)d_ws + WS_FLAGS_BYTES + (size_t)BATCH * HDIM * 2);

    hipMemsetAsync(d_ws, 0, WS_FLAGS_BYTES, stream);  // re-arm flags every launch
    hipFuncSetAttribute((const void*)ctlstm_kernel,
                        hipFuncAttributeMaxDynamicSharedMemorySize, LDS_BYTES);
    ctlstm_kernel<<<NWG, NTHREADS, LDS_BYTES, stream>>>(
        x, tdel, o_state, cs_state, ce_state, d_state,
        weight, bias, d_weight, d_bias, d_beta,
        out0, out1, flags, h0, h1);
}